// Round 1
// baseline (1406.839 us; speedup 1.0000x reference)
//
#include <hip/hip_runtime.h>
#include <math.h>

// Per-sample-weight MLP: 32 -> 512 -> 512 -> 512 -> 32 (silu, silu, silu, tanh)
// params layout per sample (row-major [out,in] weight, then bias):
//   W1[512x32] @0, b1[512] @16384,
//   W2[512x512] @16896, b2[512] @279040,
//   W3[512x512] @279552, b3[512] @541696,
//   W4[32x512] @542208, b4[32] @558592   (total 558624 floats)

#define BATCH  512
#define LATENT 32
#define HIDDEN 512
#define PCOUNT 558624

#define W1_OFF 0
#define B1_OFF 16384
#define W2_OFF 16896
#define B2_OFF 279040
#define W3_OFF 279552
#define B3_OFF 541696
#define W4_OFF 542208
#define B4_OFF 558592

__device__ __forceinline__ float silu_f(float x) {
    return x / (1.0f + expf(-x));
}

__device__ __forceinline__ float dot4(float4 a, float4 b) {
    return a.x * b.x + a.y * b.y + a.z * b.z + a.w * b.w;
}

// full-wave (64-lane) butterfly sum; all lanes end with the total
__device__ __forceinline__ float wsum64(float v) {
    v += __shfl_xor(v, 1);
    v += __shfl_xor(v, 2);
    v += __shfl_xor(v, 4);
    v += __shfl_xor(v, 8);
    v += __shfl_xor(v, 16);
    v += __shfl_xor(v, 32);
    return v;
}

// 512->512 dense layer with silu. 8 waves; wave handles 64 contiguous rows.
// hin values are preloaded to registers (ha/hb per lane), output to LDS.
__device__ __forceinline__ void layer512(const float* __restrict__ W,
                                         const float* __restrict__ bvec,
                                         const float* __restrict__ hin_lds,
                                         float* __restrict__ hout_lds,
                                         int wave, int lane) {
    float4 ha = *(const float4*)(hin_lds + 4 * lane);
    float4 hb = *(const float4*)(hin_lds + 256 + 4 * lane);
    const float* Wp = W + (size_t)wave * 64 * 512 + 4 * lane;
    const int o0 = wave * 64;
    for (int it = 0; it < 16; ++it) {
        const float* q = Wp + (size_t)it * 4 * 512;
        // 4 rows per iteration: 8 float4 loads issued before any use
        float4 a0 = *(const float4*)(q);
        float4 b0 = *(const float4*)(q + 256);
        float4 a1 = *(const float4*)(q + 512);
        float4 b1 = *(const float4*)(q + 768);
        float4 a2 = *(const float4*)(q + 1024);
        float4 b2 = *(const float4*)(q + 1280);
        float4 a3 = *(const float4*)(q + 1536);
        float4 b3 = *(const float4*)(q + 1792);
        float s0 = wsum64(dot4(a0, ha) + dot4(b0, hb));
        float s1 = wsum64(dot4(a1, ha) + dot4(b1, hb));
        float s2 = wsum64(dot4(a2, ha) + dot4(b2, hb));
        float s3 = wsum64(dot4(a3, ha) + dot4(b3, hb));
        if (lane < 4) {
            int o = o0 + it * 4 + lane;
            float s = (lane == 0) ? s0 : (lane == 1) ? s1 : (lane == 2) ? s2 : s3;
            hout_lds[o] = silu_f(s + bvec[o]);
        }
    }
}

__global__ __launch_bounds__(512) void mlp_kernel(const float* __restrict__ z,
                                                  const float* __restrict__ params,
                                                  float* __restrict__ out) {
    const int b    = blockIdx.x;
    const int tid  = threadIdx.x;
    const int wave = tid >> 6;
    const int lane = tid & 63;

    const float* __restrict__ p = params + (size_t)b * PCOUNT;

    __shared__ __align__(16) float hA[HIDDEN];
    __shared__ __align__(16) float hB[HIDDEN];

    // ---- Layer 1: 32 -> 512, silu. 8 rows per wave-iteration (8 lanes/row). ----
    {
        const int j = lane & 7;   // float4 slot within a row (8 * 4 = 32)
        const int r = lane >> 3;  // row within group of 8
        float4 zin = *(const float4*)(z + b * LATENT + 4 * j);
        #pragma unroll
        for (int it = 0; it < 8; ++it) {
            int o = wave * 64 + it * 8 + r;
            float4 w = *(const float4*)(p + W1_OFF + (size_t)o * LATENT + 4 * j);
            float acc = dot4(w, zin);
            acc += __shfl_xor(acc, 1);
            acc += __shfl_xor(acc, 2);
            acc += __shfl_xor(acc, 4);
            if (j == 0) {
                hA[o] = silu_f(acc + p[B1_OFF + o]);
            }
        }
    }
    __syncthreads();

    // ---- Layer 2: 512 -> 512, silu ----
    layer512(p + W2_OFF, p + B2_OFF, hA, hB, wave, lane);
    __syncthreads();

    // ---- Layer 3: 512 -> 512, silu ----
    layer512(p + W3_OFF, p + B3_OFF, hB, hA, wave, lane);
    __syncthreads();

    // ---- Layer 4: 512 -> 32, tanh. 4 rows per wave. ----
    {
        float4 ha = *(const float4*)(hA + 4 * lane);
        float4 hb = *(const float4*)(hA + 256 + 4 * lane);
        const float* q = p + W4_OFF + (size_t)wave * 4 * 512 + 4 * lane;
        float4 a0 = *(const float4*)(q);
        float4 b0 = *(const float4*)(q + 256);
        float4 a1 = *(const float4*)(q + 512);
        float4 b1 = *(const float4*)(q + 768);
        float4 a2 = *(const float4*)(q + 1024);
        float4 b2 = *(const float4*)(q + 1280);
        float4 a3 = *(const float4*)(q + 1536);
        float4 b3 = *(const float4*)(q + 1792);
        float s0 = wsum64(dot4(a0, ha) + dot4(b0, hb));
        float s1 = wsum64(dot4(a1, ha) + dot4(b1, hb));
        float s2 = wsum64(dot4(a2, ha) + dot4(b2, hb));
        float s3 = wsum64(dot4(a3, ha) + dot4(b3, hb));
        if (lane < 4) {
            int o = wave * 4 + lane;
            float s = (lane == 0) ? s0 : (lane == 1) ? s1 : (lane == 2) ? s2 : s3;
            out[(size_t)b * LATENT + o] = tanhf(s + p[B4_OFF + o]);
        }
    }
}

extern "C" void kernel_launch(void* const* d_in, const int* in_sizes, int n_in,
                              void* d_out, int out_size, void* d_ws, size_t ws_size,
                              hipStream_t stream) {
    // inputs: d_in[0]=t (unused scalar), d_in[1]=z [512,32] f32, d_in[2]=params [512,558624] f32
    const float* z      = (const float*)d_in[1];
    const float* params = (const float*)d_in[2];
    float* out          = (float*)d_out;
    mlp_kernel<<<BATCH, 512, 0, stream>>>(z, params, out);
}